// Round 15
// baseline (309.552 us; speedup 1.0000x reference)
//
#include <hip/hip_runtime.h>
#include <hip/hip_bf16.h>

#define B 16
#define L 64
#define P 1024
#define V 64
#define Q 16
#define LN64 4.158883083359672f

#define CHBC 16           // p per k_bc block
#define NCH_BC (P / CHBC) // 64

typedef unsigned short ushort8_t __attribute__((ext_vector_type(8)));

typedef const __attribute__((address_space(1))) void* gld_gptr_t;
typedef __attribute__((address_space(3))) void* gld_lptr_t;

static __device__ __forceinline__ float bf2f(ushort u) {
    return __uint_as_float(((unsigned int)u) << 16);
}
static __device__ __forceinline__ ushort f2bf(float f) {
    unsigned int x = __float_as_uint(f);
    unsigned int r = (x + 0x7fffu + ((x >> 16) & 1u)) >> 16;
    return (ushort)r;
}
// packed bf16-pair helpers: word = bf16(lo) | bf16(hi)<<16
static __device__ __forceinline__ float pklo(unsigned int w) {
    return __uint_as_float(w << 16);
}
static __device__ __forceinline__ float pkhi(unsigned int w) {
    return __uint_as_float(w & 0xffff0000u);
}

static __device__ __forceinline__ float wsum64(float v) {
#pragma unroll
    for (int m = 32; m > 0; m >>= 1) v += __shfl_xor(v, m, 64);
    return v;
}
static __device__ __forceinline__ float wmax64(float v) {
#pragma unroll
    for (int m = 32; m > 0; m >>= 1) v = fmaxf(v, __shfl_xor(v, m, 64));
    return v;
}

// ---------------------------------------------------------------------------
// K_uhat v14: LAYOUT CHANGE uhat[l][b][p][v] -- every prior variant (8 designs,
// all ~1.6 TB/s) wrote [b][l][p][v]: 512 isolated 128 B lines per block
// scattered over 128 MB -> DRAM row thrash (fillBuffer/linear = 6.9 TB/s;
// k_bc/16KB-contiguous = 5.8 TB/s; compact spill traffic in round 7 beat all
// "optimized" producers). New grid: block = (l, 64-p chunk) = 1024 blocks.
//  - W read: 256 KB FULLY CONTIGUOUS per block (streams, prefetch-friendly).
//  - uhat write: 16 sequential streams/block (one per b), each appending
//    128 B per p through an 8 KB region.
//  - x: packed-bf16 staged once in LDS (32 KB, [p][b][j]).
//  - W: 5-slot gld_lds ring (20 KB), 1 stage-instr/wave/tile, contiguous 1 KB
//    source with chunk-permute (s&~3)|((s&3)^((s>>4)&3)) matching the read
//    XOR q4^(vg&3) (<=4-way banks). Counted vmcnt, exact queue replay:
//    i0..3: 3,4,5,6; steady 7; i60: 7(no stage); i61: 6; i62: 5; i63: 4.
// Thread = (b = t>>4, vg = t&15): per p computes v = vg*4..+4 for its b,
// stores one uint2 (wave: 4 b x 128 B-contiguous runs).
// ---------------------------------------------------------------------------
__global__ __launch_bounds__(256) void k_uhat(const float* __restrict__ Wt,
                                              const float* __restrict__ x,
                                              ushort* __restrict__ uhat) {
    const int t = threadIdx.x;
    const int w = t >> 6;
    const int lane = t & 63;
    const int l = blockIdx.x >> 4;
    const int p0 = (blockIdx.x & 15) * 64;
    const int b = t >> 4;          // this thread's batch row
    const int vg = t & 15;         // v-quad: v = vg*4..+4
    const int xsw = vg & 3;        // read-side XOR key

    __shared__ unsigned int xls[64][B][8];   // 32 KB packed-bf16 x [p][b][j]
    __shared__ char wls[5][4096];            // 20 KB: 5-slot W-tile ring

    // stage x slice: 8192 uints; entry (p,b,j) <- pack(x[b][p0+p][2j],[2j+1])
#pragma unroll
    for (int i = 0; i < 32; ++i) {
        const int flat = i * 256 + t;
        const int bb = flat >> 9, rem = flat & 511;
        const int pp = rem >> 3, j = rem & 7;
        const float2 xv = *reinterpret_cast<const float2*>(
            x + ((size_t)bb * P + p0 + pp) * Q + 2 * j);
        xls[pp][bb][j] = (unsigned)f2bf(xv.x) | ((unsigned)f2bf(xv.y) << 16);
    }

    // W stage source: per-lane chunk s = w*64+lane of the 4 KB p-tile,
    // permuted so LDS holds W[row][q4 ^ (row>>2 & 3)] at logical pos.
    const int s = w * 64 + lane;
    const int src = (s & ~3) | ((s & 3) ^ ((s >> 4) & 3));
    const char* gW = (const char*)(Wt + ((size_t)l * P + p0) * (V * Q))
                     + (size_t)src * 16;

    ushort* ub = uhat + (((size_t)(l * B + b)) * P + p0) * V + vg * 4;

#define STAGE(pi)                                                             \
    __builtin_amdgcn_global_load_lds(                                         \
        (gld_gptr_t)(gW + (size_t)(pi) * 4096),                               \
        (gld_lptr_t)(&wls[(pi) % 5][w * 1024]), 16, 0, 0);

#define COMPUTE(pi)                                                           \
    {                                                                         \
        const unsigned int* xw = &xls[pi][b][0];                              \
        const char* sb = &wls[(pi) % 5][0];                                   \
        float d[4];                                                           \
        _Pragma("unroll")                                                     \
        for (int j = 0; j < 4; ++j) {                                         \
            const char* rb = sb + (vg * 4 + j) * 64;                          \
            const float4 W0 = *(const float4*)(rb + ((0 ^ xsw) << 4));        \
            const float4 W1 = *(const float4*)(rb + ((1 ^ xsw) << 4));        \
            const float4 W2 = *(const float4*)(rb + ((2 ^ xsw) << 4));        \
            const float4 W3 = *(const float4*)(rb + ((3 ^ xsw) << 4));        \
            float u = 0.f;                                                    \
            u = fmaf(W0.x, pklo(xw[0]), u); u = fmaf(W0.y, pkhi(xw[0]), u);   \
            u = fmaf(W0.z, pklo(xw[1]), u); u = fmaf(W0.w, pkhi(xw[1]), u);   \
            u = fmaf(W1.x, pklo(xw[2]), u); u = fmaf(W1.y, pkhi(xw[2]), u);   \
            u = fmaf(W1.z, pklo(xw[3]), u); u = fmaf(W1.w, pkhi(xw[3]), u);   \
            u = fmaf(W2.x, pklo(xw[4]), u); u = fmaf(W2.y, pkhi(xw[4]), u);   \
            u = fmaf(W2.z, pklo(xw[5]), u); u = fmaf(W2.w, pkhi(xw[5]), u);   \
            u = fmaf(W3.x, pklo(xw[6]), u); u = fmaf(W3.y, pkhi(xw[6]), u);   \
            u = fmaf(W3.z, pklo(xw[7]), u); u = fmaf(W3.w, pkhi(xw[7]), u);   \
            d[j] = u;                                                         \
        }                                                                     \
        uint2 pk;                                                             \
        pk.x = (unsigned)f2bf(d[0]) | ((unsigned)f2bf(d[1]) << 16);           \
        pk.y = (unsigned)f2bf(d[2]) | ((unsigned)f2bf(d[3]) << 16);           \
        *reinterpret_cast<uint2*>(ub + (size_t)(pi) * V) = pk;                \
    }

#define WAITB(N)                                                              \
    asm volatile("s_waitcnt vmcnt(" #N ")" ::: "memory");                     \
    __builtin_amdgcn_sched_barrier(0);                                        \
    __builtin_amdgcn_s_barrier();                                             \
    __builtin_amdgcn_sched_barrier(0);

    STAGE(0); STAGE(1); STAGE(2); STAGE(3);
    __syncthreads();   // also covers xls staging

    WAITB(3); STAGE(4); COMPUTE(0);
    WAITB(4); STAGE(5); COMPUTE(1);
    WAITB(5); STAGE(6); COMPUTE(2);
    WAITB(6); STAGE(7); COMPUTE(3);
#pragma unroll 1
    for (int pi = 4; pi <= 59; ++pi) {
        WAITB(7);
        STAGE(pi + 4);
        COMPUTE(pi);
    }
    WAITB(7); COMPUTE(60);
    WAITB(6); COMPUTE(61);
    WAITB(5); COMPUTE(62);
    WAITB(4); COMPUTE(63);

#undef STAGE
#undef COMPUTE
#undef WAITB
}

// ---------------------------------------------------------------------------
// K_s: per (b,l) block, iter-0 only (uniform c). s[v] = (1/64) sum_p u[p,v],
// fused squash. uhat[l][b][p][v]: this block's slice is 128 KB contiguous.
// ---------------------------------------------------------------------------
__global__ __launch_bounds__(256) void k_s(const ushort* __restrict__ uhat,
                                           float* __restrict__ vout) {
    const int l = blockIdx.x, b = blockIdx.y;
    const int t = threadIdx.x;
    const int w = t >> 6, lane = t & 63;
    const int pl = t >> 4;      // 0..15
    const int vg = t & 15;      // v0 = vg*4

    __shared__ float4 sl[4][16];

    const ushort* up = uhat + ((size_t)(l * B + b)) * P * V + (size_t)pl * V + vg * 4;

    float4 acc = {0.f, 0.f, 0.f, 0.f};
#pragma unroll 8
    for (int i = 0; i < 64; ++i) {
        ushort4 u = *reinterpret_cast<const ushort4*>(up + (size_t)i * 16 * V);
        acc.x += bf2f(u.x); acc.y += bf2f(u.y);
        acc.z += bf2f(u.z); acc.w += bf2f(u.w);
    }
    acc.x *= (1.f / 64.f); acc.y *= (1.f / 64.f);
    acc.z *= (1.f / 64.f); acc.w *= (1.f / 64.f);
#pragma unroll
    for (int m = 16; m <= 32; m <<= 1) {
        acc.x += __shfl_xor(acc.x, m, 64);
        acc.y += __shfl_xor(acc.y, m, 64);
        acc.z += __shfl_xor(acc.z, m, 64);
        acc.w += __shfl_xor(acc.w, m, 64);
    }
    if (lane < 16) sl[w][vg] = acc;
    __syncthreads();
    if (w == 0 && lane < 16) {
        float4 s0 = sl[0][vg], s1 = sl[1][vg], s2 = sl[2][vg], s3 = sl[3][vg];
        float4 s;
        s.x = s0.x + s1.x + s2.x + s3.x;
        s.y = s0.y + s1.y + s2.y + s3.y;
        s.z = s0.z + s1.z + s2.z + s3.z;
        s.w = s0.w + s1.w + s2.w + s3.w;
        float sq = s.x * s.x + s.y * s.y + s.z * s.z + s.w * s.w;
        sq += __shfl_xor(sq, 1, 64);
        sq += __shfl_xor(sq, 2, 64);
        sq += __shfl_xor(sq, 4, 64);
        sq += __shfl_xor(sq, 8, 64);
        float f = sqrtf(sq) / (1.0f + sq);
        float4 o = {s.x * f, s.y * f, s.z * f, s.w * f};
        *reinterpret_cast<float4*>(vout + (size_t)(b * L + l) * V + vg * 4) = o;
    }
}

// ---------------------------------------------------------------------------
// K_bc v6: block = (ch of 16 p, b), 512 threads. u tile in REGISTERS.
// uhat[l][b][p][v]: per l the 16p x 64v tile is 2 KB contiguous, l-stride
// B*P*V (2 MB). Same instruction pattern as before.
// ---------------------------------------------------------------------------
__global__ __launch_bounds__(512, 4) void k_bc(const ushort* __restrict__ uhat,
                                               const float* __restrict__ vv,
                                               float* __restrict__ bbuf,
                                               float* __restrict__ sp,
                                               float* __restrict__ Tsum,
                                               int add_prev, int do_T) {
    const int ch = blockIdx.x, b = blockIdx.y;
    const int p0 = ch * CHBC;
    const int t = threadIdx.x;
    const int w = t >> 6, lane = t & 63;
    const int pl8 = lane >> 3;   // p-local
    const int vg8 = lane & 7;    // v-octet
    const int l0 = w * 8;

    __shared__ float vsh[L][V];         // 16 KB
    __shared__ float bl[CHBC][L + 1];   // logits, then c in place
    __shared__ float twv[8];

    {
        const float4* vvp = reinterpret_cast<const float4*>(vv + (size_t)b * L * V);
        float4* vshp = reinterpret_cast<float4*>(&vsh[0][0]);
#pragma unroll
        for (int i = 0; i < 2; ++i) vshp[t + i * 512] = vvp[t + i * 512];
    }

    ushort8_t ur[8][2];
    {
        const ushort* ubase = uhat + (((size_t)(l0 * B + b)) * P + p0 + pl8) * V + vg8 * 8;
#pragma unroll
        for (int li = 0; li < 8; ++li) {
#pragma unroll
            for (int ph = 0; ph < 2; ++ph)
                ur[li][ph] = *reinterpret_cast<const ushort8_t*>(
                    ubase + (size_t)li * B * P * V + (size_t)ph * 8 * V);
        }
    }
    __syncthreads();

#pragma unroll
    for (int li = 0; li < 8; ++li) {
        const int l = l0 + li;
        const float4 va = *reinterpret_cast<const float4*>(&vsh[l][vg8 * 8]);
        const float4 vb = *reinterpret_cast<const float4*>(&vsh[l][vg8 * 8 + 4]);
#pragma unroll
        for (int ph = 0; ph < 2; ++ph) {
            float d;
            d = bf2f(ur[li][ph][0]) * va.x;
            d = fmaf(bf2f(ur[li][ph][1]), va.y, d);
            d = fmaf(bf2f(ur[li][ph][2]), va.z, d);
            d = fmaf(bf2f(ur[li][ph][3]), va.w, d);
            d = fmaf(bf2f(ur[li][ph][4]), vb.x, d);
            d = fmaf(bf2f(ur[li][ph][5]), vb.y, d);
            d = fmaf(bf2f(ur[li][ph][6]), vb.z, d);
            d = fmaf(bf2f(ur[li][ph][7]), vb.w, d);
            d += __shfl_xor(d, 1, 64);
            d += __shfl_xor(d, 2, 64);
            d += __shfl_xor(d, 4, 64);
            if (vg8 == 0) bl[ph * 8 + pl8][l] = d;
        }
    }
    __syncthreads();

    float tloc = 0.f;
#pragma unroll
    for (int pi = 0; pi < 2; ++pi) {
        const int pli = w * 2 + pi;
        const int p = p0 + pli;
        float bv = bl[pli][lane];
        float* bp = bbuf + ((size_t)b * P + p) * L;
        if (add_prev) bv += bp[lane];
        bp[lane] = bv;
        float m = wmax64(bv);
        float e = __expf(bv - m);
        float ssum = wsum64(e);
        float cc = e / ssum;
        bl[pli][lane] = cc;
        if (do_T) tloc += cc * __logf(64.0f * (cc + 1e-12f));
    }
    if (do_T) {
        float dsum = wsum64(tloc);
        if (lane == 0) twv[w] = dsum;
    }
    __syncthreads();
    if (do_T && t == 0) {
        float s8 = twv[0] + twv[1] + twv[2] + twv[3] +
                   twv[4] + twv[5] + twv[6] + twv[7];
        atomicAdd(Tsum, s8 * (1.0f / LN64));
    }

    float* spb = sp + (size_t)(b * NCH_BC + ch) * L * V;
#pragma unroll
    for (int li = 0; li < 8; ++li) {
        const int l = l0 + li;
        const float cA = bl[pl8][l];
        const float cB = bl[8 + pl8][l];
        float4 pa, pb;
        pa.x = cA * bf2f(ur[li][0][0]) + cB * bf2f(ur[li][1][0]);
        pa.y = cA * bf2f(ur[li][0][1]) + cB * bf2f(ur[li][1][1]);
        pa.z = cA * bf2f(ur[li][0][2]) + cB * bf2f(ur[li][1][2]);
        pa.w = cA * bf2f(ur[li][0][3]) + cB * bf2f(ur[li][1][3]);
        pb.x = cA * bf2f(ur[li][0][4]) + cB * bf2f(ur[li][1][4]);
        pb.y = cA * bf2f(ur[li][0][5]) + cB * bf2f(ur[li][1][5]);
        pb.z = cA * bf2f(ur[li][0][6]) + cB * bf2f(ur[li][1][6]);
        pb.w = cA * bf2f(ur[li][0][7]) + cB * bf2f(ur[li][1][7]);
#pragma unroll
        for (int m = 8; m <= 32; m <<= 1) {
            pa.x += __shfl_xor(pa.x, m, 64);
            pa.y += __shfl_xor(pa.y, m, 64);
            pa.z += __shfl_xor(pa.z, m, 64);
            pa.w += __shfl_xor(pa.w, m, 64);
            pb.x += __shfl_xor(pb.x, m, 64);
            pb.y += __shfl_xor(pb.y, m, 64);
            pb.z += __shfl_xor(pb.z, m, 64);
            pb.w += __shfl_xor(pb.w, m, 64);
        }
        if (pl8 == 0) {
            *reinterpret_cast<float4*>(spb + (size_t)l * V + vg8 * 8) = pa;
            *reinterpret_cast<float4*>(spb + (size_t)l * V + vg8 * 8 + 4) = pb;
        }
    }
}

// ---------------------------------------------------------------------------
// K_v: chunk-reduce + squash. sp[b][ch][l][v]. grid (L/4, B); wave w -> l.
// ---------------------------------------------------------------------------
__global__ __launch_bounds__(256) void k_v(const float* __restrict__ sp,
                                           float* __restrict__ vout,
                                           float* __restrict__ norms) {
    const int b = blockIdx.y;
    const int w = threadIdx.x >> 6, lane = threadIdx.x & 63;
    const int l = blockIdx.x * 4 + w;
    const float* p = sp + ((size_t)b * NCH_BC * L + l) * V + lane;
    float s = 0.f;
#pragma unroll 8
    for (int ch = 0; ch < NCH_BC; ++ch) s += p[(size_t)ch * L * V];
    float sq = wsum64(s * s);
    float f = sqrtf(sq) / (1.0f + sq);
    vout[((size_t)b * L + l) * V + lane] = s * f;
    if (norms && lane == 0) norms[b * L + l] = sq / (1.0f + sq);
}

// ---------------------------------------------------------------------------
// K_final: T and D. One block, 64 threads (lane = l).
// ---------------------------------------------------------------------------
__global__ void k_final(const float* __restrict__ Tsum,
                        const float* __restrict__ norms,
                        float* __restrict__ out) {
    const int lane = threadIdx.x & 63;
    float n[B];
    float sum = 0.f;
#pragma unroll
    for (int b = 0; b < B; ++b) { n[b] = norms[b * L + lane]; sum += n[b]; }
    const float mean = sum * (1.0f / B);
    float var = 0.f;
#pragma unroll
    for (int b = 0; b < B; ++b) { float d = n[b] - mean; var = fmaf(d, d, var); }
    var *= (1.0f / B);
    float sd = sqrtf(var);
    float D = wmax64(sd);
    if (lane == 0) {
        out[B * L * V] = Tsum[0] * (1.0f / (B * P));
        out[B * L * V + 1] = D;
    }
}

extern "C" void kernel_launch(void* const* d_in, const int* in_sizes, int n_in,
                              void* d_out, int out_size, void* d_ws, size_t ws_size,
                              hipStream_t stream) {
    const float* x = (const float*)d_in[0];   // (B,P,Q)
    const float* W = (const float*)d_in[1];   // (L,P,V,Q)
    float* out = (float*)d_out;               // v (B,L,V) then T, D

    char* ws = (char*)d_ws;
    ushort* uhat = (ushort*)ws;                        // [l][b][p][v] bf16 = 128 MB
    size_t off = (size_t)B * L * P * V * 2;
    float* spbuf = (float*)(ws + off); off += (size_t)B * NCH_BC * L * V * 4;  // 16 MB
    float* vbuf  = (float*)(ws + off); off += (size_t)B * L * V * 4;
    float* bbuf  = (float*)(ws + off); off += (size_t)B * P * L * 4;           // 4 MB [b][p][l]
    float* norms = (float*)(ws + off); off += (size_t)B * L * 4;
    float* Tsum  = (float*)(ws + off); off += 256;

    hipMemsetAsync(Tsum, 0, sizeof(float), stream);

    // u_hat: contiguous W streams, 16 sequential write streams per block
    hipLaunchKernelGGL(k_uhat, dim3(1024), dim3(256), 0, stream, W, x, uhat);
    // iter 0: uniform c -> v0
    hipLaunchKernelGGL(k_s, dim3(L, B), dim3(256), 0, stream, uhat, vbuf);
    // b1 = v0.u ; c1 ; partial s1 (fused, u in registers)
    hipLaunchKernelGGL(k_bc, dim3(NCH_BC, B), dim3(512), 0, stream,
                       uhat, vbuf, bbuf, spbuf, Tsum, 0, 0);
    // v1
    hipLaunchKernelGGL(k_v, dim3(L / 4, B), dim3(256), 0, stream,
                       spbuf, vbuf, (float*)nullptr);
    // b2 = b1 + v1.u ; c2 ; T partials ; partial s2
    hipLaunchKernelGGL(k_bc, dim3(NCH_BC, B), dim3(512), 0, stream,
                       uhat, vbuf, bbuf, spbuf, Tsum, 1, 1);
    // v2 -> out, norms
    hipLaunchKernelGGL(k_v, dim3(L / 4, B), dim3(256), 0, stream,
                       spbuf, out, norms);
    hipLaunchKernelGGL(k_final, dim3(1), dim3(64), 0, stream, Tsum, norms, out);
}

// Round 17
// 241.721 us; speedup vs baseline: 1.2806x; 1.2806x over previous
//
#include <hip/hip_runtime.h>
#include <hip/hip_bf16.h>

#define B 16
#define L 64
#define P 1024
#define V 64
#define Q 16
#define LN64 4.158883083359672f

#define CHBC 16           // p per k_bc block
#define NCH_BC (P / CHBC) // 64
#define LPV ((size_t)L * P * V)

typedef unsigned short ushort8_t __attribute__((ext_vector_type(8)));
typedef __attribute__((ext_vector_type(8))) short bf16x8;
typedef __attribute__((ext_vector_type(4))) float f32x4;

typedef const __attribute__((address_space(1))) void* gld_gptr_t;
typedef __attribute__((address_space(3))) void* gld_lptr_t;

static __device__ __forceinline__ float bf2f(ushort u) {
    return __uint_as_float(((unsigned int)u) << 16);
}
static __device__ __forceinline__ ushort f2bf(float f) {
    unsigned int x = __float_as_uint(f);
    unsigned int r = (x + 0x7fffu + ((x >> 16) & 1u)) >> 16;
    return (ushort)r;
}
static __device__ __forceinline__ unsigned pk2(float lo, float hi) {
    return (unsigned)f2bf(lo) | ((unsigned)f2bf(hi) << 16);
}

static __device__ __forceinline__ float wsum64(float v) {
#pragma unroll
    for (int m = 32; m > 0; m >>= 1) v += __shfl_xor(v, m, 64);
    return v;
}
static __device__ __forceinline__ float wmax64(float v) {
#pragma unroll
    for (int m = 32; m > 0; m >>= 1) v = fmaxf(v, __shfl_xor(v, m, 64));
    return v;
}

union FragU { uint4 u; bf16x8 s; };

// ---------------------------------------------------------------------------
// K_uhat v17: MFMA producer (round-16 structure) with ALL bf16 conversions
// done via RNE f2bf. Round 16's absmax 4.85e-3 was a systematic ~0.4% shrink
// of s -> v, consistent with v_cvt_pk_bf16_f32 truncating (RTZ): W got a
// -0.2% scale bias and the u-store another -0.2%. RNE (proven in all passing
// rounds) is unbiased. Fragment mapping unchanged (k-permutation-invariant;
// C/D = m89: col=lane&15, row=(lane>>4)*4+reg).
// Block = (ch of 32 p, l); W read 128 KB contiguous; wave-private 3-slot
// LDS ring; counted vmcnt (COMPUTE(i) always waits STAGE(i) -- replay
// verified); chained C accumulator gives fused iter-0 s0 (k_s deleted).
// ---------------------------------------------------------------------------
__global__ __launch_bounds__(256, 3) void k_uhat(const float* __restrict__ Wt,
                                                 const float* __restrict__ x,
                                                 ushort* __restrict__ uhat,
                                                 float* __restrict__ sp0) {
    const int t = threadIdx.x;
    const int w = t >> 6;
    const int lane = t & 63;
    const int kb = lane >> 4;     // k-octet / C-D row-quad
    const int cc = lane & 15;     // B col (v low bits) / C-D col
    const int ch = blockIdx.x;    // p-chunk of 32
    const int l = blockIdx.y;
    const int p0 = ch * 32;

    __shared__ __align__(16) char smem[49152];  // xstage 16KB, then 4x12KB rings
    unsigned int* xstage = (unsigned int*)smem; // [32 p][32 ln][4]

#pragma unroll
    for (int i = 0; i < 16; ++i) {
        const int e = i * 256 + t;        // 4096 entries
        const int pp = e >> 7, ln = (e >> 2) & 31, m = e & 3;
        const int b = ln & 15, qb = (ln >> 4) * 8;
        const float2 xv = *reinterpret_cast<const float2*>(
            x + ((size_t)b * P + p0 + pp) * Q + qb + 2 * m);
        xstage[e] = pk2(xv.x, xv.y);
    }
    __syncthreads();

    uint4 af[8];
#pragma unroll
    for (int i = 0; i < 8; ++i) {
        if (lane < 32)
            af[i] = *reinterpret_cast<const uint4*>(
                smem + ((size_t)(w * 8 + i) * 32 + lane) * 16);
        else
            af[i] = (uint4){0u, 0u, 0u, 0u};
    }
    __syncthreads();   // xstage dead; rings may overwrite smem

    char* ring = smem + w * 12288;        // wave-private 3 x 4 KB
    const int sperm = (lane & ~3) | ((lane & 3) ^ ((lane >> 3) & 3));
    const char* gW = (const char*)(Wt + ((size_t)l * P + p0 + w * 8) * (V * Q))
                     + (size_t)sperm * 16;
    const int xk = (cc >> 1) & 3;         // read-side chunk XOR

    f32x4 cacc0 = {0.f, 0.f, 0.f, 0.f}, cacc1 = {0.f, 0.f, 0.f, 0.f};
    f32x4 cacc2 = {0.f, 0.f, 0.f, 0.f}, cacc3 = {0.f, 0.f, 0.f, 0.f};

#define STAGE(i_)                                                             \
    {                                                                         \
        const char* s_ = gW + (size_t)(i_) * 4096;                            \
        char* d_ = ring + ((i_) % 3) * 4096;                                  \
        __builtin_amdgcn_global_load_lds((gld_gptr_t)(s_ + 0),                \
                                         (gld_lptr_t)(d_ + 0), 16, 0, 0);     \
        __builtin_amdgcn_global_load_lds((gld_gptr_t)(s_ + 1024),             \
                                         (gld_lptr_t)(d_ + 1024), 16, 0, 0);  \
        __builtin_amdgcn_global_load_lds((gld_gptr_t)(s_ + 2048),             \
                                         (gld_lptr_t)(d_ + 2048), 16, 0, 0);  \
        __builtin_amdgcn_global_load_lds((gld_gptr_t)(s_ + 3072),             \
                                         (gld_lptr_t)(d_ + 3072), 16, 0, 0);  \
    }

#define BFRAG(g_, dst_)                                                       \
    {                                                                         \
        if (lane < 32) {                                                      \
            const char* rb_ = ring + (slot_) * 4096 + (cc + 16 * (g_)) * 64;  \
            const float4 f0 =                                                 \
                *(const float4*)(rb_ + (((2 * kb + 0) ^ xk) << 4));           \
            const float4 f1 =                                                 \
                *(const float4*)(rb_ + (((2 * kb + 1) ^ xk) << 4));           \
            dst_.u = (uint4){pk2(f0.x, f0.y), pk2(f0.z, f0.w),                \
                             pk2(f1.x, f1.y), pk2(f1.z, f1.w)};               \
        } else {                                                              \
            dst_.u = (uint4){0u, 0u, 0u, 0u};                                 \
        }                                                                     \
    }

#define MMGROUP(g_, cacc_)                                                    \
    {                                                                         \
        FragU bf_;                                                            \
        BFRAG(g_, bf_);                                                       \
        f32x4 d_ = __builtin_amdgcn_mfma_f32_16x16x32_bf16(afr.s, bf_.s,      \
                                                           cacc_, 0, 0, 0);   \
        f32x4 u_ = d_ - cacc_;                                                \
        cacc_ = d_;                                                           \
        const unsigned lo01_ = pk2(u_[0], u_[1]);                             \
        const unsigned lo23_ = pk2(u_[2], u_[3]);                             \
        ushort* up_ = ub_ + (g_) * 16;                                        \
        up_[0] = (ushort)lo01_;                                               \
        up_[LPV] = (ushort)(lo01_ >> 16);                                     \
        up_[2 * LPV] = (ushort)lo23_;                                         \
        up_[3 * LPV] = (ushort)(lo23_ >> 16);                                 \
    }

#define COMPUTE(i_)                                                           \
    {                                                                         \
        const int slot_ = (i_) % 3;                                           \
        const int p_ = p0 + w * 8 + (i_);                                     \
        FragU afr; afr.u = af[i_];                                            \
        ushort* ub_ = uhat +                                                  \
            (((size_t)(kb * 4) * L + l) * P + p_) * V + cc;                   \
        MMGROUP(0, cacc0);                                                    \
        MMGROUP(1, cacc1);                                                    \
        MMGROUP(2, cacc2);                                                    \
        MMGROUP(3, cacc3);                                                    \
    }

#define WAITV(N)                                                              \
    asm volatile("s_waitcnt vmcnt(" #N ")" ::: "memory");                     \
    __builtin_amdgcn_sched_barrier(0);

    STAGE(0); STAGE(1);
    WAITV(4);  STAGE(2); COMPUTE(0);
    WAITV(16); STAGE(3); COMPUTE(1);
    WAITV(32); STAGE(4); COMPUTE(2);
    WAITV(32); STAGE(5); COMPUTE(3);
    WAITV(32); STAGE(6); COMPUTE(4);
    WAITV(32); STAGE(7); COMPUTE(5);
    WAITV(32); COMPUTE(6);
    WAITV(28); COMPUTE(7);

    // iter-0 partial s0 (raw sum over this wave's 8 p): sp0[l][ch*4+w][b][v]
    {
        float* sb = sp0 + (((size_t)l * 128 + ch * 4 + w) * 16) * 64;
#pragma unroll
        for (int i2 = 0; i2 < 4; ++i2) {
            const int b = kb * 4 + i2;
            sb[(size_t)b * 64 + cc + 0]  = cacc0[i2];
            sb[(size_t)b * 64 + cc + 16] = cacc1[i2];
            sb[(size_t)b * 64 + cc + 32] = cacc2[i2];
            sb[(size_t)b * 64 + cc + 48] = cacc3[i2];
        }
    }
#undef STAGE
#undef BFRAG
#undef MMGROUP
#undef COMPUTE
#undef WAITV
}

// ---------------------------------------------------------------------------
// K_v: generic chunk-reduce + squash. idx = cb*b + cl*l + cs*ch + v.
// ---------------------------------------------------------------------------
__global__ __launch_bounds__(256) void k_v(const float* __restrict__ sp,
                                           size_t cb, size_t cl, size_t cs,
                                           int nch, float scale,
                                           float* __restrict__ vout,
                                           float* __restrict__ norms) {
    const int b = blockIdx.y;
    const int w = threadIdx.x >> 6, lane = threadIdx.x & 63;
    const int l = blockIdx.x * 4 + w;
    const float* p = sp + cb * b + cl * l + lane;
    float s = 0.f;
#pragma unroll 8
    for (int ch = 0; ch < nch; ++ch) s += p[(size_t)ch * cs];
    s *= scale;
    float sq = wsum64(s * s);
    float f = sqrtf(sq) / (1.0f + sq);
    vout[((size_t)b * L + l) * V + lane] = s * f;
    if (norms && lane == 0) norms[b * L + l] = sq / (1.0f + sq);
}

// ---------------------------------------------------------------------------
// K_bc v6 (round-12 verbatim): block = (ch of 16 p, b), 512 threads.
// u tile in REGISTERS; phases: dot(v,u) -> softmax_l -> partial s.
// ---------------------------------------------------------------------------
__global__ __launch_bounds__(512, 4) void k_bc(const ushort* __restrict__ uhat,
                                               const float* __restrict__ vv,
                                               float* __restrict__ bbuf,
                                               float* __restrict__ sp,
                                               float* __restrict__ Tsum,
                                               int add_prev, int do_T) {
    const int ch = blockIdx.x, b = blockIdx.y;
    const int p0 = ch * CHBC;
    const int t = threadIdx.x;
    const int w = t >> 6, lane = t & 63;
    const int pl8 = lane >> 3;
    const int vg8 = lane & 7;
    const int l0 = w * 8;

    __shared__ float vsh[L][V];
    __shared__ float bl[CHBC][L + 1];
    __shared__ float twv[8];

    {
        const float4* vvp = reinterpret_cast<const float4*>(vv + (size_t)b * L * V);
        float4* vshp = reinterpret_cast<float4*>(&vsh[0][0]);
#pragma unroll
        for (int i = 0; i < 2; ++i) vshp[t + i * 512] = vvp[t + i * 512];
    }

    ushort8_t ur[8][2];
    {
        const ushort* ubase = uhat + (((size_t)(b * L + l0)) * P + p0 + pl8) * V + vg8 * 8;
#pragma unroll
        for (int li = 0; li < 8; ++li) {
#pragma unroll
            for (int ph = 0; ph < 2; ++ph)
                ur[li][ph] = *reinterpret_cast<const ushort8_t*>(
                    ubase + ((size_t)li * P + ph * 8) * V);
        }
    }
    __syncthreads();

#pragma unroll
    for (int li = 0; li < 8; ++li) {
        const int l = l0 + li;
        const float4 va = *reinterpret_cast<const float4*>(&vsh[l][vg8 * 8]);
        const float4 vb = *reinterpret_cast<const float4*>(&vsh[l][vg8 * 8 + 4]);
#pragma unroll
        for (int ph = 0; ph < 2; ++ph) {
            float d;
            d = bf2f(ur[li][ph][0]) * va.x;
            d = fmaf(bf2f(ur[li][ph][1]), va.y, d);
            d = fmaf(bf2f(ur[li][ph][2]), va.z, d);
            d = fmaf(bf2f(ur[li][ph][3]), va.w, d);
            d = fmaf(bf2f(ur[li][ph][4]), vb.x, d);
            d = fmaf(bf2f(ur[li][ph][5]), vb.y, d);
            d = fmaf(bf2f(ur[li][ph][6]), vb.z, d);
            d = fmaf(bf2f(ur[li][ph][7]), vb.w, d);
            d += __shfl_xor(d, 1, 64);
            d += __shfl_xor(d, 2, 64);
            d += __shfl_xor(d, 4, 64);
            if (vg8 == 0) bl[ph * 8 + pl8][l] = d;
        }
    }
    __syncthreads();

    float tloc = 0.f;
#pragma unroll
    for (int pi = 0; pi < 2; ++pi) {
        const int pli = w * 2 + pi;
        const int p = p0 + pli;
        float bv = bl[pli][lane];
        float* bp = bbuf + ((size_t)b * P + p) * L;
        if (add_prev) bv += bp[lane];
        bp[lane] = bv;
        float m = wmax64(bv);
        float e = __expf(bv - m);
        float ssum = wsum64(e);
        float cc = e / ssum;
        bl[pli][lane] = cc;
        if (do_T) tloc += cc * __logf(64.0f * (cc + 1e-12f));
    }
    if (do_T) {
        float dsum = wsum64(tloc);
        if (lane == 0) twv[w] = dsum;
    }
    __syncthreads();
    if (do_T && t == 0) {
        float s8 = twv[0] + twv[1] + twv[2] + twv[3] +
                   twv[4] + twv[5] + twv[6] + twv[7];
        atomicAdd(Tsum, s8 * (1.0f / LN64));
    }

    float* spb = sp + (size_t)(b * NCH_BC + ch) * L * V;
#pragma unroll
    for (int li = 0; li < 8; ++li) {
        const int l = l0 + li;
        const float cA = bl[pl8][l];
        const float cB = bl[8 + pl8][l];
        float4 pa, pb;
        pa.x = cA * bf2f(ur[li][0][0]) + cB * bf2f(ur[li][1][0]);
        pa.y = cA * bf2f(ur[li][0][1]) + cB * bf2f(ur[li][1][1]);
        pa.z = cA * bf2f(ur[li][0][2]) + cB * bf2f(ur[li][1][2]);
        pa.w = cA * bf2f(ur[li][0][3]) + cB * bf2f(ur[li][1][3]);
        pb.x = cA * bf2f(ur[li][0][4]) + cB * bf2f(ur[li][1][4]);
        pb.y = cA * bf2f(ur[li][0][5]) + cB * bf2f(ur[li][1][5]);
        pb.z = cA * bf2f(ur[li][0][6]) + cB * bf2f(ur[li][1][6]);
        pb.w = cA * bf2f(ur[li][0][7]) + cB * bf2f(ur[li][1][7]);
#pragma unroll
        for (int m = 8; m <= 32; m <<= 1) {
            pa.x += __shfl_xor(pa.x, m, 64);
            pa.y += __shfl_xor(pa.y, m, 64);
            pa.z += __shfl_xor(pa.z, m, 64);
            pa.w += __shfl_xor(pa.w, m, 64);
            pb.x += __shfl_xor(pb.x, m, 64);
            pb.y += __shfl_xor(pb.y, m, 64);
            pb.z += __shfl_xor(pb.z, m, 64);
            pb.w += __shfl_xor(pb.w, m, 64);
        }
        if (pl8 == 0) {
            *reinterpret_cast<float4*>(spb + (size_t)l * V + vg8 * 8) = pa;
            *reinterpret_cast<float4*>(spb + (size_t)l * V + vg8 * 8 + 4) = pb;
        }
    }
}

// ---------------------------------------------------------------------------
// K_final: T and D. One block, 64 threads (lane = l).
// ---------------------------------------------------------------------------
__global__ void k_final(const float* __restrict__ Tsum,
                        const float* __restrict__ norms,
                        float* __restrict__ out) {
    const int lane = threadIdx.x & 63;
    float n[B];
    float sum = 0.f;
#pragma unroll
    for (int b = 0; b < B; ++b) { n[b] = norms[b * L + lane]; sum += n[b]; }
    const float mean = sum * (1.0f / B);
    float var = 0.f;
#pragma unroll
    for (int b = 0; b < B; ++b) { float d = n[b] - mean; var = fmaf(d, d, var); }
    var *= (1.0f / B);
    float sd = sqrtf(var);
    float D = wmax64(sd);
    if (lane == 0) {
        out[B * L * V] = Tsum[0] * (1.0f / (B * P));
        out[B * L * V + 1] = D;
    }
}

extern "C" void kernel_launch(void* const* d_in, const int* in_sizes, int n_in,
                              void* d_out, int out_size, void* d_ws, size_t ws_size,
                              hipStream_t stream) {
    const float* x = (const float*)d_in[0];   // (B,P,Q)
    const float* W = (const float*)d_in[1];   // (L,P,V,Q)
    float* out = (float*)d_out;               // v (B,L,V) then T, D

    char* ws = (char*)d_ws;
    ushort* uhat = (ushort*)ws;                        // [b][l][p][v] bf16 = 128 MB
    size_t off = (size_t)B * L * P * V * 2;
    float* spbuf = (float*)(ws + off);                 // 32 MB region:
    // sp0 [l][128][16][64] (32 MB, iter-0) overlaps sp [b][64][l][v] (16 MB)
    off += (size_t)64 * 128 * 16 * 64 * 4;
    float* vbuf  = (float*)(ws + off); off += (size_t)B * L * V * 4;
    float* bbuf  = (float*)(ws + off); off += (size_t)B * P * L * 4;   // 4 MB
    float* norms = (float*)(ws + off); off += (size_t)B * L * 4;
    float* Tsum  = (float*)(ws + off); off += 256;

    hipMemsetAsync(Tsum, 0, sizeof(float), stream);

    // u_hat via MFMA (RNE conversions) + fused iter-0 s0 partials
    hipLaunchKernelGGL(k_uhat, dim3(32, 64), dim3(256), 0, stream, W, x, uhat, spbuf);
    // v0 = squash((1/64) * reduce sp0)
    hipLaunchKernelGGL(k_v, dim3(L / 4, B), dim3(256), 0, stream,
                       spbuf, (size_t)64, (size_t)131072, (size_t)1024, 128,
                       1.0f / 64.0f, vbuf, (float*)nullptr);
    // b1 = v0.u ; c1 ; partial s1 -> sp[b][ch][l][v]
    hipLaunchKernelGGL(k_bc, dim3(NCH_BC, B), dim3(512), 0, stream,
                       uhat, vbuf, bbuf, spbuf, Tsum, 0, 0);
    // v1
    hipLaunchKernelGGL(k_v, dim3(L / 4, B), dim3(256), 0, stream,
                       spbuf, (size_t)NCH_BC * L * V, (size_t)V, (size_t)L * V,
                       NCH_BC, 1.0f, vbuf, (float*)nullptr);
    // b2 = b1 + v1.u ; c2 ; T partials ; partial s2
    hipLaunchKernelGGL(k_bc, dim3(NCH_BC, B), dim3(512), 0, stream,
                       uhat, vbuf, bbuf, spbuf, Tsum, 1, 1);
    // v2 -> out, norms
    hipLaunchKernelGGL(k_v, dim3(L / 4, B), dim3(256), 0, stream,
                       spbuf, (size_t)NCH_BC * L * V, (size_t)V, (size_t)L * V,
                       NCH_BC, 1.0f, out, norms);
    hipLaunchKernelGGL(k_final, dim3(1), dim3(64), 0, stream, Tsum, norms, out);
}

// Round 18
// 220.378 us; speedup vs baseline: 1.4046x; 1.0968x over previous
//
#include <hip/hip_runtime.h>
#include <hip/hip_bf16.h>

#define B 16
#define L 64
#define P 1024
#define V 64
#define Q 16
#define LN64 4.158883083359672f

#define CHBC 16           // p per k_bc block
#define NCH_BC (P / CHBC) // 64

typedef unsigned short ushort8_t __attribute__((ext_vector_type(8)));
typedef __attribute__((ext_vector_type(8))) short bf16x8;
typedef __attribute__((ext_vector_type(4))) float f32x4;

typedef const __attribute__((address_space(1))) void* gld_gptr_t;
typedef __attribute__((address_space(3))) void* gld_lptr_t;

static __device__ __forceinline__ float bf2f(ushort u) {
    return __uint_as_float(((unsigned int)u) << 16);
}
static __device__ __forceinline__ ushort f2bf(float f) {
    unsigned int x = __float_as_uint(f);
    unsigned int r = (x + 0x7fffu + ((x >> 16) & 1u)) >> 16;
    return (ushort)r;
}
static __device__ __forceinline__ unsigned pk2(float lo, float hi) {
    return (unsigned)f2bf(lo) | ((unsigned)f2bf(hi) << 16);
}

static __device__ __forceinline__ float wsum64(float v) {
#pragma unroll
    for (int m = 32; m > 0; m >>= 1) v += __shfl_xor(v, m, 64);
    return v;
}
static __device__ __forceinline__ float wmax64(float v) {
#pragma unroll
    for (int m = 32; m > 0; m >>= 1) v = fmaxf(v, __shfl_xor(v, m, 64));
    return v;
}

union FragU { uint4 u; bf16x8 s; };

// ---------------------------------------------------------------------------
// K_uhat v18: SWAPPED-OPERAND MFMA + sv-permuted [l][p][b][sv] layout.
// v17's wall was the write path: C/D layout (cols=v) forced 4x2B scattered
// stores per MMGROUP -> 4x32B quarter-lines/instr, WRITE_SIZE 270MB (1.65x
// amplification), 2.15 TB/s. Swap: D = mfma(A=W-frag, B=x-frag) -> rows=v,
// cols=b; lane (kb,cc) holds u[b=cc][v=g*16+kb*4+i2]. Define sv = kb*16 +
// i2*4 + g: each lane's 16 values are sv-consecutive -> TWO uint4 stores,
// 32B/lane; wave instr = 1KB fully contiguous; block streams 64KB.
// sv is a fixed v-permutation: dots & |.|^2 invariant; vbuf/sp stay in sv
// space; only final k_v write un-permutes. sp0 = 4x float4 contiguous.
// Fragment layouts reused from v17 (HW-verified by its pass): A: m=lane&15,
// k-octet=lane>>4 (k>=16 zeroed via x-frag); old BFRAG (W) is now A-frag.
// Waits by exact queue replay (2 st/step), margin -2: 2,4,6,6,6,6,6,2.
// ---------------------------------------------------------------------------
__global__ __launch_bounds__(256, 3) void k_uhat(const float* __restrict__ Wt,
                                                 const float* __restrict__ x,
                                                 ushort* __restrict__ uhat,
                                                 float* __restrict__ sp0) {
    const int t = threadIdx.x;
    const int w = t >> 6;
    const int lane = t & 63;
    const int kb = lane >> 4;     // k-octet / D row-quad (v-quad)
    const int cc = lane & 15;     // D col = b ; A row = v low bits
    const int ch = blockIdx.x;    // p-chunk of 32
    const int l = blockIdx.y;
    const int p0 = ch * 32;

    __shared__ __align__(16) char smem[49152];  // xstage 16KB, then 4x12KB rings
    unsigned int* xstage = (unsigned int*)smem; // [32 p][32 ln][4]

#pragma unroll
    for (int i = 0; i < 16; ++i) {
        const int e = i * 256 + t;        // 4096 entries
        const int pp = e >> 7, ln = (e >> 2) & 31, m = e & 3;
        const int b = ln & 15, qb = (ln >> 4) * 8;
        const float2 xv = *reinterpret_cast<const float2*>(
            x + ((size_t)b * P + p0 + pp) * Q + qb + 2 * m);
        xstage[e] = pk2(xv.x, xv.y);
    }
    __syncthreads();

    uint4 af[8];                  // x B-frags (zeros for lane>=32 -> k>=16)
#pragma unroll
    for (int i = 0; i < 8; ++i) {
        if (lane < 32)
            af[i] = *reinterpret_cast<const uint4*>(
                smem + ((size_t)(w * 8 + i) * 32 + lane) * 16);
        else
            af[i] = (uint4){0u, 0u, 0u, 0u};
    }
    __syncthreads();   // xstage dead; rings may overwrite smem

    char* ring = smem + w * 12288;        // wave-private 3 x 4 KB
    const int sperm = (lane & ~3) | ((lane & 3) ^ ((lane >> 3) & 3));
    const char* gW = (const char*)(Wt + ((size_t)l * P + p0 + w * 8) * (V * Q))
                     + (size_t)sperm * 16;
    const int xk = (cc >> 1) & 3;         // read-side chunk XOR

    f32x4 cacc0 = {0.f, 0.f, 0.f, 0.f}, cacc1 = {0.f, 0.f, 0.f, 0.f};
    f32x4 cacc2 = {0.f, 0.f, 0.f, 0.f}, cacc3 = {0.f, 0.f, 0.f, 0.f};

#define STAGE(i_)                                                             \
    {                                                                         \
        const char* s_ = gW + (size_t)(i_) * 4096;                            \
        char* d_ = ring + ((i_) % 3) * 4096;                                  \
        __builtin_amdgcn_global_load_lds((gld_gptr_t)(s_ + 0),                \
                                         (gld_lptr_t)(d_ + 0), 16, 0, 0);     \
        __builtin_amdgcn_global_load_lds((gld_gptr_t)(s_ + 1024),             \
                                         (gld_lptr_t)(d_ + 1024), 16, 0, 0);  \
        __builtin_amdgcn_global_load_lds((gld_gptr_t)(s_ + 2048),             \
                                         (gld_lptr_t)(d_ + 2048), 16, 0, 0);  \
        __builtin_amdgcn_global_load_lds((gld_gptr_t)(s_ + 3072),             \
                                         (gld_lptr_t)(d_ + 3072), 16, 0, 0);  \
    }

// A-frag = W rows v = g*16 + cc, k-octet kb (kb>=2 -> zero, covered by x=0)
#define WFRAG(g_, dst_)                                                       \
    {                                                                         \
        if (lane < 32) {                                                      \
            const char* rb_ = ring + (slot_) * 4096 + (cc + 16 * (g_)) * 64;  \
            const float4 f0 =                                                 \
                *(const float4*)(rb_ + (((2 * kb + 0) ^ xk) << 4));           \
            const float4 f1 =                                                 \
                *(const float4*)(rb_ + (((2 * kb + 1) ^ xk) << 4));           \
            dst_.u = (uint4){pk2(f0.x, f0.y), pk2(f0.z, f0.w),                \
                             pk2(f1.x, f1.y), pk2(f1.z, f1.w)};               \
        } else {                                                              \
            dst_.u = (uint4){0u, 0u, 0u, 0u};                                 \
        }                                                                     \
    }

#define MMG(g_, cacc_, u_)                                                    \
    {                                                                         \
        FragU wf_;                                                            \
        WFRAG(g_, wf_);                                                       \
        f32x4 d_ = __builtin_amdgcn_mfma_f32_16x16x32_bf16(wf_.s, bx_.s,      \
                                                           cacc_, 0, 0, 0);   \
        u_ = d_ - cacc_;                                                      \
        cacc_ = d_;                                                           \
    }

#define COMPUTE(i_)                                                           \
    {                                                                         \
        const int slot_ = (i_) % 3;                                           \
        const int p_ = p0 + w * 8 + (i_);                                     \
        FragU bx_; bx_.u = af[i_];                                            \
        f32x4 u0_, u1_, u2_, u3_;                                             \
        MMG(0, cacc0, u0_);                                                   \
        MMG(1, cacc1, u1_);                                                   \
        MMG(2, cacc2, u2_);                                                   \
        MMG(3, cacc3, u3_);                                                   \
        uint4 A_, B_;                                                         \
        A_.x = pk2(u0_[0], u1_[0]); A_.y = pk2(u2_[0], u3_[0]);               \
        A_.z = pk2(u0_[1], u1_[1]); A_.w = pk2(u2_[1], u3_[1]);               \
        B_.x = pk2(u0_[2], u1_[2]); B_.y = pk2(u2_[2], u3_[2]);               \
        B_.z = pk2(u0_[3], u1_[3]); B_.w = pk2(u2_[3], u3_[3]);               \
        ushort* ub_ = uhat + (((size_t)l * P + p_) * B + cc) * V + kb * 16;   \
        *reinterpret_cast<uint4*>(ub_) = A_;                                  \
        *reinterpret_cast<uint4*>(ub_ + 8) = B_;                              \
    }

#define WAITV(N)                                                              \
    asm volatile("s_waitcnt vmcnt(" #N ")" ::: "memory");                     \
    __builtin_amdgcn_sched_barrier(0);

    STAGE(0); STAGE(1);
    WAITV(2); STAGE(2); COMPUTE(0);
    WAITV(4); STAGE(3); COMPUTE(1);
    WAITV(6); STAGE(4); COMPUTE(2);
    WAITV(6); STAGE(5); COMPUTE(3);
    WAITV(6); STAGE(6); COMPUTE(4);
    WAITV(6); STAGE(7); COMPUTE(5);
    WAITV(6); COMPUTE(6);
    WAITV(2); COMPUTE(7);

    // iter-0 partial s0: sp0[l][ch*4+w][b=cc][sv], 4x float4 contiguous
    {
        float* sb = sp0 + (((size_t)l * 128 + ch * 4 + w) * 16 + cc) * 64 + kb * 16;
        float4 q0 = {cacc0[0], cacc1[0], cacc2[0], cacc3[0]};
        float4 q1 = {cacc0[1], cacc1[1], cacc2[1], cacc3[1]};
        float4 q2 = {cacc0[2], cacc1[2], cacc2[2], cacc3[2]};
        float4 q3 = {cacc0[3], cacc1[3], cacc2[3], cacc3[3]};
        *reinterpret_cast<float4*>(sb + 0) = q0;
        *reinterpret_cast<float4*>(sb + 4) = q1;
        *reinterpret_cast<float4*>(sb + 8) = q2;
        *reinterpret_cast<float4*>(sb + 12) = q3;
    }
#undef STAGE
#undef WFRAG
#undef MMG
#undef COMPUTE
#undef WAITV
}

// ---------------------------------------------------------------------------
// K_v: generic chunk-reduce + squash (sv space). unperm=1 -> write true-v.
// ---------------------------------------------------------------------------
__global__ __launch_bounds__(256) void k_v(const float* __restrict__ sp,
                                           size_t cb, size_t cl, size_t cs,
                                           int nch, float scale, int unperm,
                                           float* __restrict__ vout,
                                           float* __restrict__ norms) {
    const int b = blockIdx.y;
    const int w = threadIdx.x >> 6, lane = threadIdx.x & 63;
    const int l = blockIdx.x * 4 + w;
    const float* p = sp + cb * b + cl * l + lane;
    float s = 0.f;
#pragma unroll 8
    for (int ch = 0; ch < nch; ++ch) s += p[(size_t)ch * cs];
    s *= scale;
    float sq = wsum64(s * s);
    float f = sqrtf(sq) / (1.0f + sq);
    const int vi = unperm ? ((lane & 3) * 16 + (lane >> 4) * 4 + ((lane >> 2) & 3))
                          : lane;
    vout[((size_t)b * L + l) * V + vi] = s * f;
    if (norms && lane == 0) norms[b * L + l] = sq / (1.0f + sq);
}

// ---------------------------------------------------------------------------
// K_bc: block = (ch of 16 p, b), 512 threads. u tile in REGISTERS.
// uhat layout [l][p][b][sv]: per (l,p,b) the sv-run is 128B contiguous.
// All v-space math is in sv space (vbuf/vsh/sp all sv) -- invariant.
// ---------------------------------------------------------------------------
__global__ __launch_bounds__(512, 4) void k_bc(const ushort* __restrict__ uhat,
                                               const float* __restrict__ vv,
                                               float* __restrict__ bbuf,
                                               float* __restrict__ sp,
                                               float* __restrict__ Tsum,
                                               int add_prev, int do_T) {
    const int ch = blockIdx.x, b = blockIdx.y;
    const int p0 = ch * CHBC;
    const int t = threadIdx.x;
    const int w = t >> 6, lane = t & 63;
    const int pl8 = lane >> 3;
    const int vg8 = lane & 7;
    const int l0 = w * 8;

    __shared__ float vsh[L][V];
    __shared__ float bl[CHBC][L + 1];
    __shared__ float twv[8];

    {
        const float4* vvp = reinterpret_cast<const float4*>(vv + (size_t)b * L * V);
        float4* vshp = reinterpret_cast<float4*>(&vsh[0][0]);
#pragma unroll
        for (int i = 0; i < 2; ++i) vshp[t + i * 512] = vvp[t + i * 512];
    }

    const size_t LSTR = (size_t)P * B * V;   // l stride
    ushort8_t ur[8][2];
    {
        const ushort* ubase = uhat + (((size_t)l0 * P + p0 + pl8) * B + b) * V + vg8 * 8;
#pragma unroll
        for (int li = 0; li < 8; ++li) {
#pragma unroll
            for (int ph = 0; ph < 2; ++ph)
                ur[li][ph] = *reinterpret_cast<const ushort8_t*>(
                    ubase + (size_t)li * LSTR + (size_t)ph * 8 * B * V);
        }
    }
    __syncthreads();

#pragma unroll
    for (int li = 0; li < 8; ++li) {
        const int l = l0 + li;
        const float4 va = *reinterpret_cast<const float4*>(&vsh[l][vg8 * 8]);
        const float4 vb = *reinterpret_cast<const float4*>(&vsh[l][vg8 * 8 + 4]);
#pragma unroll
        for (int ph = 0; ph < 2; ++ph) {
            float d;
            d = bf2f(ur[li][ph][0]) * va.x;
            d = fmaf(bf2f(ur[li][ph][1]), va.y, d);
            d = fmaf(bf2f(ur[li][ph][2]), va.z, d);
            d = fmaf(bf2f(ur[li][ph][3]), va.w, d);
            d = fmaf(bf2f(ur[li][ph][4]), vb.x, d);
            d = fmaf(bf2f(ur[li][ph][5]), vb.y, d);
            d = fmaf(bf2f(ur[li][ph][6]), vb.z, d);
            d = fmaf(bf2f(ur[li][ph][7]), vb.w, d);
            d += __shfl_xor(d, 1, 64);
            d += __shfl_xor(d, 2, 64);
            d += __shfl_xor(d, 4, 64);
            if (vg8 == 0) bl[ph * 8 + pl8][l] = d;
        }
    }
    __syncthreads();

    float tloc = 0.f;
#pragma unroll
    for (int pi = 0; pi < 2; ++pi) {
        const int pli = w * 2 + pi;
        const int p = p0 + pli;
        float bv = bl[pli][lane];
        float* bp = bbuf + ((size_t)b * P + p) * L;
        if (add_prev) bv += bp[lane];
        bp[lane] = bv;
        float m = wmax64(bv);
        float e = __expf(bv - m);
        float ssum = wsum64(e);
        float cc = e / ssum;
        bl[pli][lane] = cc;
        if (do_T) tloc += cc * __logf(64.0f * (cc + 1e-12f));
    }
    if (do_T) {
        float dsum = wsum64(tloc);
        if (lane == 0) twv[w] = dsum;
    }
    __syncthreads();
    if (do_T && t == 0) {
        float s8 = twv[0] + twv[1] + twv[2] + twv[3] +
                   twv[4] + twv[5] + twv[6] + twv[7];
        atomicAdd(Tsum, s8 * (1.0f / LN64));
    }

    float* spb = sp + (size_t)(b * NCH_BC + ch) * L * V;
#pragma unroll
    for (int li = 0; li < 8; ++li) {
        const int l = l0 + li;
        const float cA = bl[pl8][l];
        const float cB = bl[8 + pl8][l];
        float4 pa, pb;
        pa.x = cA * bf2f(ur[li][0][0]) + cB * bf2f(ur[li][1][0]);
        pa.y = cA * bf2f(ur[li][0][1]) + cB * bf2f(ur[li][1][1]);
        pa.z = cA * bf2f(ur[li][0][2]) + cB * bf2f(ur[li][1][2]);
        pa.w = cA * bf2f(ur[li][0][3]) + cB * bf2f(ur[li][1][3]);
        pb.x = cA * bf2f(ur[li][0][4]) + cB * bf2f(ur[li][1][4]);
        pb.y = cA * bf2f(ur[li][0][5]) + cB * bf2f(ur[li][1][5]);
        pb.z = cA * bf2f(ur[li][0][6]) + cB * bf2f(ur[li][1][6]);
        pb.w = cA * bf2f(ur[li][0][7]) + cB * bf2f(ur[li][1][7]);
#pragma unroll
        for (int m = 8; m <= 32; m <<= 1) {
            pa.x += __shfl_xor(pa.x, m, 64);
            pa.y += __shfl_xor(pa.y, m, 64);
            pa.z += __shfl_xor(pa.z, m, 64);
            pa.w += __shfl_xor(pa.w, m, 64);
            pb.x += __shfl_xor(pb.x, m, 64);
            pb.y += __shfl_xor(pb.y, m, 64);
            pb.z += __shfl_xor(pb.z, m, 64);
            pb.w += __shfl_xor(pb.w, m, 64);
        }
        if (pl8 == 0) {
            *reinterpret_cast<float4*>(spb + (size_t)l * V + vg8 * 8) = pa;
            *reinterpret_cast<float4*>(spb + (size_t)l * V + vg8 * 8 + 4) = pb;
        }
    }
}

// ---------------------------------------------------------------------------
// K_final: T and D. One block, 64 threads (lane = l).
// ---------------------------------------------------------------------------
__global__ void k_final(const float* __restrict__ Tsum,
                        const float* __restrict__ norms,
                        float* __restrict__ out) {
    const int lane = threadIdx.x & 63;
    float n[B];
    float sum = 0.f;
#pragma unroll
    for (int b = 0; b < B; ++b) { n[b] = norms[b * L + lane]; sum += n[b]; }
    const float mean = sum * (1.0f / B);
    float var = 0.f;
#pragma unroll
    for (int b = 0; b < B; ++b) { float d = n[b] - mean; var = fmaf(d, d, var); }
    var *= (1.0f / B);
    float sd = sqrtf(var);
    float D = wmax64(sd);
    if (lane == 0) {
        out[B * L * V] = Tsum[0] * (1.0f / (B * P));
        out[B * L * V + 1] = D;
    }
}

extern "C" void kernel_launch(void* const* d_in, const int* in_sizes, int n_in,
                              void* d_out, int out_size, void* d_ws, size_t ws_size,
                              hipStream_t stream) {
    const float* x = (const float*)d_in[0];   // (B,P,Q)
    const float* W = (const float*)d_in[1];   // (L,P,V,Q)
    float* out = (float*)d_out;               // v (B,L,V) then T, D

    char* ws = (char*)d_ws;
    ushort* uhat = (ushort*)ws;                        // [l][p][b][sv] bf16 = 128 MB
    size_t off = (size_t)B * L * P * V * 2;
    float* spbuf = (float*)(ws + off);                 // 32 MB region:
    // sp0 [l][128][16][64] (32 MB, iter-0) overlaps sp [b][64][l][v] (16 MB)
    off += (size_t)64 * 128 * 16 * 64 * 4;
    float* vbuf  = (float*)(ws + off); off += (size_t)B * L * V * 4;
    float* bbuf  = (float*)(ws + off); off += (size_t)B * P * L * 4;   // 4 MB
    float* norms = (float*)(ws + off); off += (size_t)B * L * 4;
    float* Tsum  = (float*)(ws + off); off += 256;

    hipMemsetAsync(Tsum, 0, sizeof(float), stream);

    // u_hat via swapped-operand MFMA, 1KB-coalesced stores + fused s0
    hipLaunchKernelGGL(k_uhat, dim3(32, 64), dim3(256), 0, stream, W, x, uhat, spbuf);
    // v0 = squash((1/64) * reduce sp0)   (sv space)
    hipLaunchKernelGGL(k_v, dim3(L / 4, B), dim3(256), 0, stream,
                       spbuf, (size_t)64, (size_t)131072, (size_t)1024, 128,
                       1.0f / 64.0f, 0, vbuf, (float*)nullptr);
    // b1 = v0.u ; c1 ; partial s1 -> sp[b][ch][l][sv]
    hipLaunchKernelGGL(k_bc, dim3(NCH_BC, B), dim3(512), 0, stream,
                       uhat, vbuf, bbuf, spbuf, Tsum, 0, 0);
    // v1 (sv space)
    hipLaunchKernelGGL(k_v, dim3(L / 4, B), dim3(256), 0, stream,
                       spbuf, (size_t)NCH_BC * L * V, (size_t)V, (size_t)L * V,
                       NCH_BC, 1.0f, 0, vbuf, (float*)nullptr);
    // b2 = b1 + v1.u ; c2 ; T partials ; partial s2
    hipLaunchKernelGGL(k_bc, dim3(NCH_BC, B), dim3(512), 0, stream,
                       uhat, vbuf, bbuf, spbuf, Tsum, 1, 1);
    // v2 -> out (un-permuted to true v), norms
    hipLaunchKernelGGL(k_v, dim3(L / 4, B), dim3(256), 0, stream,
                       spbuf, (size_t)NCH_BC * L * V, (size_t)V, (size_t)L * V,
                       NCH_BC, 1.0f, 1, out, norms);
    hipLaunchKernelGGL(k_final, dim3(1), dim3(64), 0, stream, Tsum, norms, out);
}